// Round 1
// baseline (409.299 us; speedup 1.0000x reference)
//
#include <hip/hip_runtime.h>
#include <hip/hip_bf16.h>

// out = data @ (mask*weight)^T + bias
// data  [8192,4096] f32, weight [4096,4096] f32, mask [4096,4096] f32, bias [4096] f32
// Strategy: convert to bf16 (tolerance is ~2% rel -> bf16-safe), MFMA GEMM.

#define GM 8192
#define GN 4096
#define GK 4096

typedef __attribute__((ext_vector_type(8))) short short8;
typedef __attribute__((ext_vector_type(8))) short bf16x8;
typedef __attribute__((ext_vector_type(4))) float f32x4;

__device__ __forceinline__ short f2bf(float x) {
    // round-to-nearest-even bf16 truncation (inputs are normal randoms, no NaN)
    unsigned u = __builtin_bit_cast(unsigned, x);
    u += 0x7fffu + ((u >> 16) & 1u);
    return (short)(u >> 16);
}

__device__ __forceinline__ void gload_lds16(const short* g, short* l) {
    __builtin_amdgcn_global_load_lds(
        (const __attribute__((address_space(1))) unsigned int*)g,
        (__attribute__((address_space(3))) unsigned int*)l, 16, 0, 0);
}

// --- conversion: data f32 -> bf16 ---
__global__ void cvt_data_kernel(const float* __restrict__ in, short* __restrict__ out, long n) {
    long i0 = ((long)blockIdx.x * blockDim.x + threadIdx.x) * 8;
    long stride = (long)gridDim.x * blockDim.x * 8;
    for (long i = i0; i < n; i += stride) {
        float4 a = *(const float4*)(in + i);
        float4 b = *(const float4*)(in + i + 4);
        short8 o;
        o[0] = f2bf(a.x); o[1] = f2bf(a.y); o[2] = f2bf(a.z); o[3] = f2bf(a.w);
        o[4] = f2bf(b.x); o[5] = f2bf(b.y); o[6] = f2bf(b.z); o[7] = f2bf(b.w);
        *(short8*)(out + i) = o;
    }
}

// --- conversion: (mask * weight) f32 -> bf16 ---
__global__ void cvt_w_kernel(const float* __restrict__ w, const float* __restrict__ m,
                             short* __restrict__ out, long n) {
    long i0 = ((long)blockIdx.x * blockDim.x + threadIdx.x) * 8;
    long stride = (long)gridDim.x * blockDim.x * 8;
    for (long i = i0; i < n; i += stride) {
        float4 wa = *(const float4*)(w + i);
        float4 wb = *(const float4*)(w + i + 4);
        float4 ma = *(const float4*)(m + i);
        float4 mb = *(const float4*)(m + i + 4);
        short8 o;
        o[0] = f2bf(wa.x * ma.x); o[1] = f2bf(wa.y * ma.y);
        o[2] = f2bf(wa.z * ma.z); o[3] = f2bf(wa.w * ma.w);
        o[4] = f2bf(wb.x * mb.x); o[5] = f2bf(wb.y * mb.y);
        o[6] = f2bf(wb.z * mb.z); o[7] = f2bf(wb.w * mb.w);
        *(short8*)(out + i) = o;
    }
}

// --- bf16 NT GEMM: C[M][N] = A[M][K] * B[N][K]^T + bias ---
// m97 structure: 128x128 tile, BK=32, 4 waves (2x2), 4x4 16x16x32 fragments/wave,
// linear LDS + global_load_lds width 16, 2 barriers per K-step.
__global__ __launch_bounds__(256) void gemm_bf16_kernel(const short* __restrict__ A,
                                                        const short* __restrict__ B,
                                                        const float* __restrict__ bias,
                                                        float* __restrict__ C) {
    __shared__ __align__(16) short lA[128 * 32];  // 8 KB
    __shared__ __align__(16) short lB[128 * 32];  // 8 KB

    const int tid  = threadIdx.x;
    const int lane = tid & 63;
    const int wid  = tid >> 6;

    // XCD-aware bijective swizzle: nwg = 2048, divisible by 8
    const int bid = blockIdx.x;
    const int swz = (bid & 7) * 256 + (bid >> 3);
    const int tm = swz >> 5;   // 64 M-tiles
    const int tn = swz & 31;   // 32 N-tiles
    const int brow = tm << 7;
    const int bcol = tn << 7;

    const int wr = wid >> 1;   // wave row (0..1), owns 64 rows
    const int wc = wid & 1;    // wave col (0..1), owns 64 cols

    f32x4 acc[4][4] = {};

    // staging lane geometry: chunk = 16 rows x 32 bf16 (1 KB); lane covers 16 B
    const int srow = lane >> 2;        // row within chunk
    const int scol = (lane & 3) << 3;  // bf16 element offset in row
    const int c0 = wid * 2;            // each wave stages 2 chunks of A and of B

    const int l15 = lane & 15;
    const int kc  = (lane >> 4) << 3;  // k-group element offset for fragments

    for (int k0 = 0; k0 < GK; k0 += 32) {
        __syncthreads();  // previous tile fully consumed
        #pragma unroll
        for (int cc = 0; cc < 2; ++cc) {
            const int c = c0 + cc;
            const int r = c * 16 + srow;
            gload_lds16(A + (size_t)(brow + r) * GK + k0 + scol, &lA[c * 512]);
            gload_lds16(B + (size_t)(bcol + r) * GK + k0 + scol, &lB[c * 512]);
        }
        __syncthreads();  // staging complete (compiler drains vmcnt)

        bf16x8 af[4], bfr[4];
        #pragma unroll
        for (int m = 0; m < 4; ++m)
            af[m] = *(const bf16x8*)&lA[(wr * 64 + m * 16 + l15) * 32 + kc];
        #pragma unroll
        for (int n = 0; n < 4; ++n)
            bfr[n] = *(const bf16x8*)&lB[(wc * 64 + n * 16 + l15) * 32 + kc];

        #pragma unroll
        for (int m = 0; m < 4; ++m)
            #pragma unroll
            for (int n = 0; n < 4; ++n)
                acc[m][n] = __builtin_amdgcn_mfma_f32_16x16x32_bf16(af[m], bfr[n], acc[m][n], 0, 0, 0);
    }

    // epilogue: C/D layout col = lane&15, row = (lane>>4)*4 + r  (m89-verified)
    #pragma unroll
    for (int n = 0; n < 4; ++n) {
        const int col = bcol + wc * 64 + n * 16 + l15;
        const float bv = bias[col];
        #pragma unroll
        for (int m = 0; m < 4; ++m) {
            const int rowb = brow + wr * 64 + m * 16 + ((lane >> 4) << 2);
            #pragma unroll
            for (int r = 0; r < 4; ++r)
                C[(size_t)(rowb + r) * GN + col] = acc[m][n][r] + bv;
        }
    }
}

extern "C" void kernel_launch(void* const* d_in, const int* in_sizes, int n_in,
                              void* d_out, int out_size, void* d_ws, size_t ws_size,
                              hipStream_t stream) {
    const float* data   = (const float*)d_in[0];  // [8192,4096]
    const float* weight = (const float*)d_in[1];  // [4096,4096]
    const float* mask   = (const float*)d_in[2];  // [4096,4096]
    const float* bias   = (const float*)d_in[3];  // [4096]
    float* out = (float*)d_out;

    short* dataB = (short*)d_ws;                     // 64 MB bf16 data
    short* wB    = dataB + (size_t)GM * GK;          // 32 MB bf16 masked weight

    cvt_data_kernel<<<2048, 256, 0, stream>>>(data, dataB, (long)GM * GK);
    cvt_w_kernel<<<2048, 256, 0, stream>>>(weight, mask, wB, (long)GN * GK);

    // grid = (8192/128) * (4096/128) = 64 * 32 = 2048 workgroups
    gemm_bf16_kernel<<<2048, 256, 0, stream>>>(dataB, wB, bias, out);
}

// Round 2
// 309.969 us; speedup vs baseline: 1.3205x; 1.3205x over previous
//
#include <hip/hip_runtime.h>
#include <hip/hip_bf16.h>

// out = data @ (mask*weight)^T + bias, via bf16 MFMA.
// Round 2: 256x256 tile, BK=32, 4-deep LDS ring, counted-vmcnt pipeline
// (T2 swizzle + T3/T4 counted waits + T5 setprio), 8 waves.

#define GM 8192
#define GN 4096
#define GK 4096
#define NT (GK / 32)   // 128 K-tiles

typedef __attribute__((ext_vector_type(8))) short short8;
typedef __attribute__((ext_vector_type(8))) short bf16x8;
typedef __attribute__((ext_vector_type(4))) float f32x4;

__device__ __forceinline__ short f2bf(float x) {
    unsigned u = __builtin_bit_cast(unsigned, x);
    u += 0x7fffu + ((u >> 16) & 1u);
    return (short)(u >> 16);
}

__device__ __forceinline__ void stage16(const short* g, short* l) {
    __builtin_amdgcn_global_load_lds(
        (const __attribute__((address_space(1))) unsigned int*)g,
        (__attribute__((address_space(3))) unsigned int*)l, 16, 0, 0);
}

// --- conversion: data f32 -> bf16 ---
__global__ void cvt_data_kernel(const float* __restrict__ in, short* __restrict__ out, long n) {
    long i0 = ((long)blockIdx.x * blockDim.x + threadIdx.x) * 8;
    long stride = (long)gridDim.x * blockDim.x * 8;
    for (long i = i0; i < n; i += stride) {
        float4 a = *(const float4*)(in + i);
        float4 b = *(const float4*)(in + i + 4);
        short8 o;
        o[0] = f2bf(a.x); o[1] = f2bf(a.y); o[2] = f2bf(a.z); o[3] = f2bf(a.w);
        o[4] = f2bf(b.x); o[5] = f2bf(b.y); o[6] = f2bf(b.z); o[7] = f2bf(b.w);
        *(short8*)(out + i) = o;
    }
}

// --- conversion: (mask * weight) f32 -> bf16 ---
__global__ void cvt_w_kernel(const float* __restrict__ w, const float* __restrict__ m,
                             short* __restrict__ out, long n) {
    long i0 = ((long)blockIdx.x * blockDim.x + threadIdx.x) * 8;
    long stride = (long)gridDim.x * blockDim.x * 8;
    for (long i = i0; i < n; i += stride) {
        float4 wa = *(const float4*)(w + i);
        float4 wb = *(const float4*)(w + i + 4);
        float4 ma = *(const float4*)(m + i);
        float4 mb = *(const float4*)(m + i + 4);
        short8 o;
        o[0] = f2bf(wa.x * ma.x); o[1] = f2bf(wa.y * ma.y);
        o[2] = f2bf(wa.z * ma.z); o[3] = f2bf(wa.w * ma.w);
        o[4] = f2bf(wb.x * mb.x); o[5] = f2bf(wb.y * mb.y);
        o[6] = f2bf(wb.z * mb.z); o[7] = f2bf(wb.w * mb.w);
        *(short8*)(out + i) = o;
    }
}

// --- deep-pipelined bf16 NT GEMM ---
// LDS map (shorts): ring r (0..3) at r*16384; A halves at +0,+4096; B halves at +8192,+12288.
// Half = [128 rows][32 cols] bf16, row = 64 B, quarter-swizzled:
//   stored quarter = logical quarter ^ (((row>>3)&1)<<1 | ((row>>1)&1))
__global__ __launch_bounds__(512, 2) void gemm_8w(const short* __restrict__ A,
                                                  const short* __restrict__ B,
                                                  const float* __restrict__ bias,
                                                  float* __restrict__ C) {
    __shared__ short lds[65536];  // 128 KB

    const int tid  = threadIdx.x;
    const int lane = tid & 63;
    const int wid  = tid >> 6;   // 0..7
    const int wr   = wid >> 2;   // 0..1  (wave row: 128 rows)
    const int wc   = wid & 3;    // 0..3  (wave col: 64 cols)

    // XCD-aware bijective swizzle: nwg = 512, % 8 == 0
    const int bid  = blockIdx.x;
    const int swz  = (bid & 7) * 64 + (bid >> 3);
    const int brow = (swz >> 4) << 8;   // 32 M-tiles
    const int bcol = (swz & 15) << 8;   // 16 N-tiles

    // ---- staging constants (pre-swizzled global source; linear LDS dest) ----
    const int lrow  = tid >> 2;                 // 0..127 row within half
    const int q_log = (tid & 3) ^ ((((lrow >> 3) & 1) << 1) | ((lrow >> 1) & 1));
    const size_t aSrc0 = (size_t)(brow + lrow) * GK + q_log * 8;
    const size_t bSrc0 = (size_t)(bcol + lrow) * GK + q_log * 8;

    // ---- fragment-read constants (swizzled LDS read) ----
    const int l15 = lane & 15;
    const int q   = lane >> 4;
    const int qx  = (((l15 >> 3) & 1) << 1) | ((l15 >> 1) & 1);
    const int foff = l15 * 32 + ((q ^ qx) << 3);              // shorts, within half
    const int aOff = wr * 4096 + foff;                        // + ring + m*512
    const int bOff = 8192 + (wc >> 1) * 4096 + (wc & 1) * 2048 + foff;  // + ring + n*512

    f32x4 acc[8][4] = {};

    auto stageA = [&](int t) {
        const int ring = (t & 3) * 16384;
        const size_t k = (size_t)t * 32;
        #pragma unroll
        for (int h = 0; h < 2; ++h)
            stage16(A + aSrc0 + (size_t)h * 128 * GK + k, &lds[ring + h * 4096 + wid * 512]);
    };
    auto stageB = [&](int t) {
        const int ring = (t & 3) * 16384;
        const size_t k = (size_t)t * 32;
        #pragma unroll
        for (int h = 0; h < 2; ++h)
            stage16(B + bSrc0 + (size_t)h * 128 * GK + k, &lds[ring + 8192 + h * 4096 + wid * 512]);
    };

    // ---- prologue: stage tiles 0,1,2 (12 loads); tile 0 landed when vmcnt<=8 ----
    stageA(0); stageB(0);
    stageA(1); stageB(1);
    stageA(2); stageB(2);
    asm volatile("s_waitcnt vmcnt(8)" ::: "memory");
    __builtin_amdgcn_s_barrier();

    for (int T = 0; T < NT; ++T) {
        const int ring = (T & 3) * 16384;
        bf16x8 af[4], bf[4];

        // ---- phase 0: read A m0-3 + B n0-3, stage A of tile T+3 ----
        #pragma unroll
        for (int m = 0; m < 4; ++m) af[m] = *(const bf16x8*)&lds[ring + aOff + m * 512];
        #pragma unroll
        for (int n = 0; n < 4; ++n) bf[n] = *(const bf16x8*)&lds[ring + bOff + n * 512];
        if (T + 3 < NT) stageA(T + 3);
        __builtin_amdgcn_s_barrier();
        asm volatile("s_waitcnt lgkmcnt(0)" ::: "memory");
        __builtin_amdgcn_sched_barrier(0);
        __builtin_amdgcn_s_setprio(1);
        #pragma unroll
        for (int m = 0; m < 4; ++m)
            #pragma unroll
            for (int n = 0; n < 4; ++n)
                acc[m][n] = __builtin_amdgcn_mfma_f32_16x16x32_bf16(af[m], bf[n], acc[m][n], 0, 0, 0);
        __builtin_amdgcn_s_setprio(0);
        __builtin_amdgcn_s_barrier();

        // ---- phase 1: read A m4-7 (B reused), stage B of tile T+3 ----
        #pragma unroll
        for (int m = 0; m < 4; ++m) af[m] = *(const bf16x8*)&lds[ring + aOff + (m + 4) * 512];
        if (T + 3 < NT) stageB(T + 3);
        __builtin_amdgcn_s_barrier();
        asm volatile("s_waitcnt lgkmcnt(0)" ::: "memory");
        __builtin_amdgcn_sched_barrier(0);
        __builtin_amdgcn_s_setprio(1);
        #pragma unroll
        for (int m = 0; m < 4; ++m)
            #pragma unroll
            for (int n = 0; n < 4; ++n)
                acc[m + 4][n] = __builtin_amdgcn_mfma_f32_16x16x32_bf16(af[m], bf[n], acc[m + 4][n], 0, 0, 0);
        __builtin_amdgcn_s_setprio(0);

        // ---- counted vmcnt once per tile: keep 2 tiles (8 loads) in flight ----
        if (T < NT - 3)       { asm volatile("s_waitcnt vmcnt(8)" ::: "memory"); }
        else if (T == NT - 3) { asm volatile("s_waitcnt vmcnt(4)" ::: "memory"); }
        else if (T == NT - 2) { asm volatile("s_waitcnt vmcnt(0)" ::: "memory"); }
        __builtin_amdgcn_s_barrier();
    }

    // ---- epilogue: C/D layout col = lane&15, row = (lane>>4)*4 + r ----
    #pragma unroll
    for (int n = 0; n < 4; ++n) {
        const int col = bcol + wc * 64 + n * 16 + l15;
        const float bv = bias[col];
        #pragma unroll
        for (int m = 0; m < 8; ++m) {
            const int rowb = brow + wr * 128 + m * 16 + (q << 2);
            #pragma unroll
            for (int r = 0; r < 4; ++r)
                C[(size_t)(rowb + r) * GN + col] = acc[m][n][r] + bv;
        }
    }
}

extern "C" void kernel_launch(void* const* d_in, const int* in_sizes, int n_in,
                              void* d_out, int out_size, void* d_ws, size_t ws_size,
                              hipStream_t stream) {
    const float* data   = (const float*)d_in[0];  // [8192,4096]
    const float* weight = (const float*)d_in[1];  // [4096,4096]
    const float* mask   = (const float*)d_in[2];  // [4096,4096]
    const float* bias   = (const float*)d_in[3];  // [4096]
    float* out = (float*)d_out;

    short* dataB = (short*)d_ws;                  // 64 MB bf16 data
    short* wB    = dataB + (size_t)GM * GK;       // 32 MB bf16 masked weight

    cvt_data_kernel<<<2048, 256, 0, stream>>>(data, dataB, (long)GM * GK);
    cvt_w_kernel<<<2048, 256, 0, stream>>>(weight, mask, wB, (long)GN * GK);

    // grid = (8192/256) * (4096/256) = 32 * 16 = 512 workgroups, 8 waves each
    gemm_8w<<<512, 512, 0, stream>>>(dataB, wB, bias, out);
}

// Round 4
// 296.746 us; speedup vs baseline: 1.3793x; 1.0446x over previous
//
#include <hip/hip_runtime.h>
#include <hip/hip_bf16.h>

// out = data @ (mask*weight)^T + bias, via bf16 MFMA.
// Round 4: same schedule as R3 (256x256 tile, BK=32, 4-deep LDS ring, counted
// vmcnt + compiler-counted lgkmcnt register prefetch, 1 barrier/K-tile) with
// the prologue race fixed: vmcnt(8) -> vmcnt(4) so tiles 0 AND 1 are landed
// before tile 0's phase-1 prefetch of tile 1.

#define GM 8192
#define GN 4096
#define GK 4096
#define NT (GK / 32)   // 128 K-tiles

typedef __attribute__((ext_vector_type(8))) short short8;
typedef __attribute__((ext_vector_type(8))) short bf16x8;
typedef __attribute__((ext_vector_type(4))) float f32x4;

__device__ __forceinline__ short f2bf(float x) {
    unsigned u = __builtin_bit_cast(unsigned, x);
    u += 0x7fffu + ((u >> 16) & 1u);
    return (short)(u >> 16);
}

__device__ __forceinline__ void stage16(const short* g, short* l) {
    __builtin_amdgcn_global_load_lds(
        (const __attribute__((address_space(1))) unsigned int*)g,
        (__attribute__((address_space(3))) unsigned int*)l, 16, 0, 0);
}

// --- conversion: data f32 -> bf16 ---
__global__ void cvt_data_kernel(const float* __restrict__ in, short* __restrict__ out, long n) {
    long i0 = ((long)blockIdx.x * blockDim.x + threadIdx.x) * 8;
    long stride = (long)gridDim.x * blockDim.x * 8;
    for (long i = i0; i < n; i += stride) {
        float4 a = *(const float4*)(in + i);
        float4 b = *(const float4*)(in + i + 4);
        short8 o;
        o[0] = f2bf(a.x); o[1] = f2bf(a.y); o[2] = f2bf(a.z); o[3] = f2bf(a.w);
        o[4] = f2bf(b.x); o[5] = f2bf(b.y); o[6] = f2bf(b.z); o[7] = f2bf(b.w);
        *(short8*)(out + i) = o;
    }
}

// --- conversion: (mask * weight) f32 -> bf16 ---
__global__ void cvt_w_kernel(const float* __restrict__ w, const float* __restrict__ m,
                             short* __restrict__ out, long n) {
    long i0 = ((long)blockIdx.x * blockDim.x + threadIdx.x) * 8;
    long stride = (long)gridDim.x * blockDim.x * 8;
    for (long i = i0; i < n; i += stride) {
        float4 wa = *(const float4*)(w + i);
        float4 wb = *(const float4*)(w + i + 4);
        float4 ma = *(const float4*)(m + i);
        float4 mb = *(const float4*)(m + i + 4);
        short8 o;
        o[0] = f2bf(wa.x * ma.x); o[1] = f2bf(wa.y * ma.y);
        o[2] = f2bf(wa.z * ma.z); o[3] = f2bf(wa.w * ma.w);
        o[4] = f2bf(wb.x * mb.x); o[5] = f2bf(wb.y * mb.y);
        o[6] = f2bf(wb.z * mb.z); o[7] = f2bf(wb.w * mb.w);
        *(short8*)(out + i) = o;
    }
}

// --- deep-pipelined bf16 NT GEMM ---
// LDS map (shorts): ring r (0..3) at r*16384; A halves at +0,+4096; B at +8192,+12288.
// Half = [128 rows][32 cols] bf16, quarter-swizzled:
//   stored quarter = logical quarter ^ (((row>>3)&1)<<1 | ((row>>1)&1))
//
// Schedule per K-tile T (2 phases, ONE barrier at tile end):
//  p0: stageA(T+3); ds_read AF_P1 <- A4-7(T); MFMA(AF_P0 x BF_CUR) -> acc[0..3]
//  p1: stageB(T+3); ds_read AF_P0 <- A0-3(T+1), BF_NXT <- B(T+1);
//      MFMA(AF_P1 x BF_CUR) -> acc[4..7]; vmcnt(4); barrier
//
// Staging invariant (by induction): at entry to tile T, all tiles <= T+1 are
// landed in LDS. Base case: prologue issues tiles 0,1,2 (12 loads) and waits
// vmcnt(4) -> 8 oldest (tiles 0,1) complete. Step: end-of-tile-T vmcnt(4)
// leaves only tile T+3's 4 loads outstanding -> tile T+2 landed.
// WAR: stage(T+3) writes ring[(T-1)&3]; last reads of that slot (tile T-1
// phase 0) are consumed by tile T-1 phase-1 MFMAs (compiler lgkmcnt) before
// the end-of-tile barrier that precedes the stage. Disjoint otherwise.
__global__ __launch_bounds__(512, 2) void gemm_8w(const short* __restrict__ A,
                                                  const short* __restrict__ B,
                                                  const float* __restrict__ bias,
                                                  float* __restrict__ C) {
    __shared__ short lds[65536];  // 128 KB

    const int tid  = threadIdx.x;
    const int lane = tid & 63;
    const int wid  = tid >> 6;   // 0..7
    const int wr   = wid >> 2;   // 0..1  (wave row: 128 rows)
    const int wc   = wid & 3;    // 0..3  (wave col: 64 cols)

    // XCD-aware bijective swizzle: nwg = 512, % 8 == 0
    const int bid  = blockIdx.x;
    const int swz  = (bid & 7) * 64 + (bid >> 3);
    const int brow = (swz >> 4) << 8;   // 32 M-tiles
    const int bcol = (swz & 15) << 8;   // 16 N-tiles

    // ---- staging constants (pre-swizzled global source; linear LDS dest) ----
    const int lrow  = tid >> 2;                 // 0..127 row within half
    const int q_log = (tid & 3) ^ ((((lrow >> 3) & 1) << 1) | ((lrow >> 1) & 1));
    const size_t aSrc0 = (size_t)(brow + lrow) * GK + q_log * 8;
    const size_t bSrc0 = (size_t)(bcol + lrow) * GK + q_log * 8;

    // ---- fragment-read constants (swizzled LDS read) ----
    const int l15 = lane & 15;
    const int q   = lane >> 4;
    const int qx  = (((l15 >> 3) & 1) << 1) | ((l15 >> 1) & 1);
    const int foff = l15 * 32 + ((q ^ qx) << 3);              // shorts, within half
    const int aOff = wr * 4096 + foff;                        // + ring + m*512
    const int bOff = 8192 + (wc >> 1) * 4096 + (wc & 1) * 2048 + foff;  // + ring + n*512

    f32x4 acc[8][4] = {};
    bf16x8 afA[4], afB[4], bfA[4], bfB[4];

    auto stageA = [&](int t) {
        const int ring = (t & 3) * 16384;
        const size_t k = (size_t)t * 32;
        #pragma unroll
        for (int h = 0; h < 2; ++h)
            stage16(A + aSrc0 + (size_t)h * 128 * GK + k, &lds[ring + h * 4096 + wid * 512]);
    };
    auto stageB = [&](int t) {
        const int ring = (t & 3) * 16384;
        const size_t k = (size_t)t * 32;
        #pragma unroll
        for (int h = 0; h < 2; ++h)
            stage16(B + bSrc0 + (size_t)h * 128 * GK + k, &lds[ring + 8192 + h * 4096 + wid * 512]);
    };

    // ---- prologue: stage tiles 0,1,2; confirm tiles 0 AND 1 landed ----
    stageA(0); stageB(0);
    stageA(1); stageB(1);
    stageA(2); stageB(2);
    asm volatile("s_waitcnt vmcnt(4)" ::: "memory");  // tiles 0,1 landed (FIX: was vmcnt(8))
    __builtin_amdgcn_s_barrier();
    asm volatile("" ::: "memory");
    #pragma unroll
    for (int m = 0; m < 4; ++m) afA[m] = *(const bf16x8*)&lds[aOff + m * 512];
    #pragma unroll
    for (int n = 0; n < 4; ++n) bfA[n] = *(const bf16x8*)&lds[bOff + n * 512];

#define TILE_BODY(T, AF_P0, AF_P1, BF_CUR, BF_NXT)                                 \
  {                                                                                 \
    const int ring  = ((T) & 3) * 16384;                                            \
    const int ringN = (((T) + 1) & 3) * 16384;                                      \
    /* ---- phase 0 ---- */                                                         \
    if ((T) + 3 < NT) stageA((T) + 3);                                              \
    _Pragma("unroll")                                                               \
    for (int m = 0; m < 4; ++m)                                                     \
      AF_P1[m] = *(const bf16x8*)&lds[ring + aOff + (m + 4) * 512];                 \
    __builtin_amdgcn_sched_barrier(0);                                              \
    __builtin_amdgcn_s_setprio(1);                                                  \
    _Pragma("unroll")                                                               \
    for (int m = 0; m < 4; ++m)                                                     \
      _Pragma("unroll")                                                             \
      for (int n = 0; n < 4; ++n)                                                   \
        acc[m][n] = __builtin_amdgcn_mfma_f32_16x16x32_bf16(AF_P0[m], BF_CUR[n],    \
                                                            acc[m][n], 0, 0, 0);    \
    __builtin_amdgcn_s_setprio(0);                                                  \
    /* ---- phase 1 (no barrier between phases: slots disjoint at ring-4) ---- */   \
    if ((T) + 3 < NT) stageB((T) + 3);                                              \
    _Pragma("unroll")                                                               \
    for (int m = 0; m < 4; ++m)                                                     \
      AF_P0[m] = *(const bf16x8*)&lds[ringN + aOff + m * 512];                      \
    _Pragma("unroll")                                                               \
    for (int n = 0; n < 4; ++n)                                                     \
      BF_NXT[n] = *(const bf16x8*)&lds[ringN + bOff + n * 512];                     \
    __builtin_amdgcn_sched_barrier(0);                                              \
    __builtin_amdgcn_s_setprio(1);                                                  \
    _Pragma("unroll")                                                               \
    for (int m = 0; m < 4; ++m)                                                     \
      _Pragma("unroll")                                                             \
      for (int n = 0; n < 4; ++n)                                                   \
        acc[m + 4][n] = __builtin_amdgcn_mfma_f32_16x16x32_bf16(AF_P1[m], BF_CUR[n],\
                                                                acc[m + 4][n], 0, 0, 0); \
    __builtin_amdgcn_s_setprio(0);                                                  \
    if ((T) + 3 < NT) { asm volatile("s_waitcnt vmcnt(4)" ::: "memory"); }          \
    else              { asm volatile("s_waitcnt vmcnt(0)" ::: "memory"); }          \
    __builtin_amdgcn_s_barrier();                                                   \
    asm volatile("" ::: "memory");                                                  \
  }

    for (int T = 0; T < NT; T += 2) {
        TILE_BODY(T,     afA, afB, bfA, bfB);   // even tile: B in bfA, next B -> bfB
        TILE_BODY(T + 1, afA, afB, bfB, bfA);   // odd tile:  B in bfB, next B -> bfA
    }
#undef TILE_BODY

    // ---- epilogue: C/D layout col = lane&15, row = (lane>>4)*4 + r ----
    #pragma unroll
    for (int n = 0; n < 4; ++n) {
        const int col = bcol + wc * 64 + n * 16 + l15;
        const float bv = bias[col];
        #pragma unroll
        for (int m = 0; m < 8; ++m) {
            const int rowb = brow + wr * 128 + m * 16 + (q << 2);
            #pragma unroll
            for (int r = 0; r < 4; ++r)
                C[(size_t)(rowb + r) * GN + col] = acc[m][n][r] + bv;
        }
    }
}

extern "C" void kernel_launch(void* const* d_in, const int* in_sizes, int n_in,
                              void* d_out, int out_size, void* d_ws, size_t ws_size,
                              hipStream_t stream) {
    const float* data   = (const float*)d_in[0];  // [8192,4096]
    const float* weight = (const float*)d_in[1];  // [4096,4096]
    const float* mask   = (const float*)d_in[2];  // [4096,4096]
    const float* bias   = (const float*)d_in[3];  // [4096]
    float* out = (float*)d_out;

    short* dataB = (short*)d_ws;                  // 64 MB bf16 data
    short* wB    = dataB + (size_t)GM * GK;       // 32 MB bf16 masked weight

    cvt_data_kernel<<<2048, 256, 0, stream>>>(data, dataB, (long)GM * GK);
    cvt_w_kernel<<<2048, 256, 0, stream>>>(weight, mask, wB, (long)GN * GK);

    // grid = (8192/256) * (4096/256) = 32 * 16 = 512 workgroups, 8 waves each
    gemm_8w<<<512, 512, 0, stream>>>(dataB, wB, bias, out);
}